// Round 12
// baseline (95.840 us; speedup 1.0000x reference)
//
#include <hip/hip_runtime.h>

// DependencyGenerator, R12: ONE kernel, no workspace, no memset.
// 256 blocks x 256 thr grid-stride float4 fill (proven pattern; stride
// window == one row => block b exclusively owns floats [b*1024,(b+1)*1024)
// of every row, i.e. scatter targets with idx>>10==b).
// While fill stores drain, each block scans the full entry list (coalesced,
// L2-resident) and inserts its owned entries into an LDS hash
// (pack = k<<19 | row<<10 | idxlow; atomicMax => max-k = numpy last-dup-wins).
// __syncthreads drains the block's own fill stores; then winners store
// dep_emb[dep_type[row*511+k]] to block-exclusive addresses.

#define SEQ_L   512
#define LM1     511
#define ROWELEM (SEQ_L * SEQ_L)     // 262144 floats per row
#define NT      256
#define BLOCKS  256                 // owner = idx>>10 in [0,256)
#define HSLOTS  1024                // ~255 keys/block -> load 0.25

typedef float vfloat4 __attribute__((ext_vector_type(4)));

__device__ __forceinline__ unsigned hash_key(unsigned key) {
    return (key * 2654435761u) >> 22;          // 10 bits
}

__global__ __launch_bounds__(NT) void depmask_onepass(
    const int*   __restrict__ dep_i,
    const int*   __restrict__ dep_j,
    const int*   __restrict__ dep_type,
    const float* __restrict__ dep_emb,
    float*       __restrict__ out,
    unsigned int n4, int nent)
{
    __shared__ int      h_key[HSLOTS];
    __shared__ unsigned h_pack[HSLOTS];

    const int b = blockIdx.x;
    const int t = threadIdx.x;

    #pragma unroll
    for (int h = t; h < HSLOTS; h += NT) { h_key[h] = -1; h_pack[h] = 0; }
    __syncthreads();    // hash init visible before any cross-thread inserts

    // Phase F: issue all fill stores (fire-and-forget, HBM-write-bound).
    {
        const vfloat4 ones = {1.f, 1.f, 1.f, 1.f};
        vfloat4* o4 = reinterpret_cast<vfloat4*>(out);
        const unsigned stride = BLOCKS * NT;   // 65536 f4 = ROWELEM floats
        unsigned i = (unsigned)b * NT + t;
        #pragma unroll 4
        for (; i < n4; i += stride)
            o4[i] = ones;
    }

    // Phase S (hides under the store drain): scan ALL entries, coalesced
    // (lane t reads e = m*NT+t); keep those owned by this block; insert
    // into LDS hash. LDS-only side effects => legal before the barrier.
    for (int e = t; e < nent; e += NT) {
        const int idx = dep_i[e] * SEQ_L + dep_j[e];
        if ((idx >> 10) == b) {
            const int row = e / LM1;           // magic-mul div (const 511)
            const int k   = e - row * LM1;     // per-row ordinal
            const unsigned pack = ((unsigned)k << 19) | ((unsigned)row << 10)
                                | ((unsigned)idx & 1023u);
            const unsigned key = pack & 0x7FFFFu;    // row<<10 | idxlow
            unsigned h = hash_key(key);
            while (true) {
                int prev = atomicCAS(&h_key[h], -1, (int)key);
                if (prev == -1 || prev == (int)key) {
                    atomicMax(&h_pack[h], pack);     // max k wins
                    break;
                }
                h = (h + 1) & (HSLOTS - 1);
            }
        }
    }

    // Drains vmcnt(0): this block's fill stores complete. Scatter targets
    // below are written exclusively by this block -> no cross-block order.
    __syncthreads();

    // Phase W: one pass over the hash; winners re-derive val and store.
    #pragma unroll
    for (int h = t; h < HSLOTS; h += NT) {
        if (h_key[h] != -1) {
            const unsigned pack = h_pack[h];
            const int k   = (int)(pack >> 19);
            const int row = (int)((pack >> 10) & 0x1FFu);
            const int ty  = dep_type[row * LM1 + k];   // L2-hot
            out[(size_t)row * ROWELEM + ((size_t)b << 10) + (pack & 1023u)]
                = dep_emb[ty];                          // 53-entry, L1
        }
    }
}

extern "C" void kernel_launch(void* const* d_in, const int* in_sizes, int n_in,
                              void* d_out, int out_size, void* d_ws, size_t ws_size,
                              hipStream_t stream) {
    const int*   dep_i    = (const int*)  d_in[0];
    const int*   dep_j    = (const int*)  d_in[1];
    const int*   dep_type = (const int*)  d_in[2];
    // d_in[3] = seq_len scalar (512)
    const float* dep_emb  = (const float*)d_in[4];
    float*       out      = (float*)      d_out;

    const int nent = in_sizes[0];                      // 128*511 = 65408
    const int rows = nent / LM1;                       // 128
    const unsigned int n4 = (unsigned int)((size_t)rows * ROWELEM / 4);

    depmask_onepass<<<dim3(BLOCKS), dim3(NT), 0, stream>>>(
        dep_i, dep_j, dep_type, dep_emb, out, n4, nent);
}

// Round 13
// 27.797 us; speedup vs baseline: 3.4478x; 3.4478x over previous
//
#include <hip/hip_runtime.h>

// DependencyGenerator, R13: ONE kernel, ownership fusion, reads-before-stores.
// Block b = (row r = b>>1, half h = b&1). Phase order is the whole trick:
//   A: load emb table (53 f) + this row's 511 (i,j,type) -> regs/LDS
//   B: __syncthreads (cheap; no big store queue yet)
//   C: fill own half-row: 512 KB contiguous, 128 float4 stores/thread
//   D: LDS-hash insert of own-half entries — pure LDS/VALU, NO vmem use,
//      so it genuinely overlaps the store drain (R12 died on vmcnt FIFO:
//      loads after stores can't complete until the stores drain).
//   E: __syncthreads -> own fill stores complete; targets idx>>17==h are
//      block-exclusive, so no cross-block ordering needed.
//   F: winners (atomicMax pack = k<<17|idxlow -> numpy last-dup-wins) store.

#define SEQ_L   512
#define LM1     511
#define ROWELEM (SEQ_L * SEQ_L)      // 262144 floats per row
#define HALF    (ROWELEM / 2)        // 131072 floats (2^17)
#define NT      256
#define HSLOTS  1024                 // ~256 keys -> load 0.25
#define NEMBMAX 64

typedef float vfloat4 __attribute__((ext_vector_type(4)));

__device__ __forceinline__ unsigned hash_key(unsigned key) {
    return (key * 2654435761u) >> 22;            // 10 bits
}

__global__ __launch_bounds__(NT) void depmask_fused(
    const int*   __restrict__ dep_i,
    const int*   __restrict__ dep_j,
    const int*   __restrict__ dep_type,
    const float* __restrict__ dep_emb,
    float*       __restrict__ out,
    int nemb)
{
    __shared__ int      h_key[HSLOTS];
    __shared__ unsigned h_pack[HSLOTS];
    __shared__ float    s_emb[NEMBMAX];

    const int b   = blockIdx.x;
    const int row = b >> 1;
    const int hlf = b & 1;
    const int t   = threadIdx.x;

    // Phase A: all global reads up front.
    if (t < nemb) s_emb[t] = dep_emb[t];
    #pragma unroll
    for (int s = t; s < HSLOTS; s += NT) { h_key[s] = -1; h_pack[s] = 0; }

    const int base = row * LM1;
    const int k0 = t, k1 = t + NT;
    const int idx0 = dep_i[base + k0] * SEQ_L + dep_j[base + k0];
    const int ty0  = dep_type[base + k0];
    int idx1 = -1, ty1 = 0;
    if (k1 < LM1) {
        idx1 = dep_i[base + k1] * SEQ_L + dep_j[base + k1];
        ty1  = dep_type[base + k1];
    }

    // Phase B: table/hash-init visible; staged loads complete (small).
    __syncthreads();

    const float val0 = s_emb[ty0];
    const float val1 = (idx1 >= 0) ? s_emb[ty1] : 0.f;

    // Phase C: fill own half-row (contiguous 512 KB; 1 KB/wave-front sweep).
    {
        const vfloat4 ones = {1.f, 1.f, 1.f, 1.f};
        vfloat4* o4 = reinterpret_cast<vfloat4*>(out)
                    + (size_t)row * (ROWELEM / 4) + (size_t)hlf * (HALF / 4);
        #pragma unroll 4
        for (int it = 0; it < HALF / 4 / NT; ++it)     // 128 stores
            o4[it * NT + t] = ones;
    }

    // Phase D: hash-insert own-half entries (LDS/VALU only -> overlaps drain).
    if ((idx0 >> 17) == hlf) {
        const unsigned key = (unsigned)idx0 & 0x1FFFFu;
        const unsigned pack = ((unsigned)k0 << 17) | key;
        unsigned s = hash_key(key);
        while (true) {
            int prev = atomicCAS(&h_key[s], -1, (int)key);
            if (prev == -1 || prev == (int)key) { atomicMax(&h_pack[s], pack); break; }
            s = (s + 1) & (HSLOTS - 1);
        }
    }
    if (idx1 >= 0 && (idx1 >> 17) == hlf) {
        const unsigned key = (unsigned)idx1 & 0x1FFFFu;
        const unsigned pack = ((unsigned)k1 << 17) | key;
        unsigned s = hash_key(key);
        while (true) {
            int prev = atomicCAS(&h_key[s], -1, (int)key);
            if (prev == -1 || prev == (int)key) { atomicMax(&h_pack[s], pack); break; }
            s = (s + 1) & (HSLOTS - 1);
        }
    }

    // Phase E: drains own fill stores; hash stable.
    __syncthreads();

    // Phase F: winner-check (pack equality) -> scatter store own val.
    if ((idx0 >> 17) == hlf) {
        const unsigned key = (unsigned)idx0 & 0x1FFFFu;
        const unsigned pack = ((unsigned)k0 << 17) | key;
        unsigned s = hash_key(key);
        while (h_key[s] != (int)key) s = (s + 1) & (HSLOTS - 1);
        if (h_pack[s] == pack) out[(size_t)row * ROWELEM + idx0] = val0;
    }
    if (idx1 >= 0 && (idx1 >> 17) == hlf) {
        const unsigned key = (unsigned)idx1 & 0x1FFFFu;
        const unsigned pack = ((unsigned)k1 << 17) | key;
        unsigned s = hash_key(key);
        while (h_key[s] != (int)key) s = (s + 1) & (HSLOTS - 1);
        if (h_pack[s] == pack) out[(size_t)row * ROWELEM + idx1] = val1;
    }
}

extern "C" void kernel_launch(void* const* d_in, const int* in_sizes, int n_in,
                              void* d_out, int out_size, void* d_ws, size_t ws_size,
                              hipStream_t stream) {
    const int*   dep_i    = (const int*)  d_in[0];
    const int*   dep_j    = (const int*)  d_in[1];
    const int*   dep_type = (const int*)  d_in[2];
    // d_in[3] = seq_len scalar (512)
    const float* dep_emb  = (const float*)d_in[4];
    float*       out      = (float*)      d_out;

    const int rows = in_sizes[0] / LM1;          // 128
    const int nemb = in_sizes[4];                // 53

    depmask_fused<<<dim3(2 * rows), dim3(NT), 0, stream>>>(
        dep_i, dep_j, dep_type, dep_emb, out, nemb);
}